// Round 4
// baseline (759.230 us; speedup 1.0000x reference)
//
#include <hip/hip_runtime.h>

typedef __attribute__((address_space(3))) unsigned int lds_u32;
typedef const __attribute__((address_space(1))) unsigned int glb_u32;

// async 16B global -> LDS (global_load_lds_dwordx4). HW dest = wave-uniform
// base + lane*16, which our flat slot layout satisfies exactly.
__device__ __forceinline__ void gload16(const float* g, float* l) {
    __builtin_amdgcn_global_load_lds((glb_u32*)g, (lds_u32*)l, 16, 0, 0);
}

// ---------------- CSR build: direct global-atomic path ----------------
// Replaces the 5-kernel bucket sort (~90 MB moved) with ~51 MB + global
// atomics (3.2M adds over 100k counters, ~32 avg contention).

__global__ __launch_bounds__(256) void k_deg(const int* __restrict__ dst, int E,
                                             int* __restrict__ hist) {
    int stride = gridDim.x * 256;
    for (int e = blockIdx.x * 256 + threadIdx.x; e < E; e += stride)
        atomicAdd(&hist[dst[e]], 1);
}

// per-256-node-block exclusive scan of hist -> local rowStart + block sums
__global__ __launch_bounds__(256) void k_scan_local(const int* __restrict__ hist, int N,
                                                    int* __restrict__ rowStart,
                                                    int* __restrict__ bsums) {
    __shared__ int s[2][256];
    int t = threadIdx.x, b = blockIdx.x;
    int node = b * 256 + t;
    int v = (node < N) ? hist[node] : 0;
    int p = 0;
    s[0][t] = v;
    __syncthreads();
    for (int off = 1; off < 256; off <<= 1) {
        s[p ^ 1][t] = s[p][t] + ((t >= off) ? s[p][t - off] : 0);
        p ^= 1;
        __syncthreads();
    }
    if (node < N) rowStart[node] = s[p][t] - v;  // exclusive within block
    if (t == 255) bsums[b] = s[p][t];            // block total
}

// single block, 512 threads; exclusive scan in place (n <= 512)
__global__ void k_scan_bsums(int* bsums, int nb) {
    __shared__ int s[2][512];
    int t = threadIdx.x;
    int v = (t < nb) ? bsums[t] : 0;
    int p = 0;
    s[0][t] = v;
    __syncthreads();
    for (int off = 1; off < 512; off <<= 1) {
        s[p ^ 1][t] = s[p][t] + ((t >= off) ? s[p][t - off] : 0);
        p ^= 1;
        __syncthreads();
    }
    if (t < nb) bsums[t] = s[p][t] - v;  // exclusive
}

// rowStart += block base; dinv from degree; zero the scatter cursors
__global__ __launch_bounds__(256) void k_finalize(int* __restrict__ rowStart,
                                                  const int* __restrict__ bsums,
                                                  const int* __restrict__ hist,
                                                  int N, float* __restrict__ dinv,
                                                  int* __restrict__ cnt) {
    int i = blockIdx.x * 256 + threadIdx.x;  // blockIdx.x == i>>8 (256/block)
    if (i < N) {
        rowStart[i] += bsums[blockIdx.x];
        dinv[i] = rsqrtf((float)(hist[i] + 1));  // +1 self-loop
        cnt[i] = 0;
    }
}

__global__ __launch_bounds__(256) void k_csr_scatter(const int* __restrict__ src,
                                                     const int* __restrict__ dst, int E,
                                                     const int* __restrict__ rowStart,
                                                     int* __restrict__ cnt,
                                                     int* __restrict__ csr_src) {
    int stride = gridDim.x * 256;
    for (int e = blockIdx.x * 256 + threadIdx.x; e < E; e += stride) {
        int d = dst[e];
        int r = atomicAdd(&cnt[d], 1);
        csr_src[rowStart[d] + r] = src[e];  // L2-resident scatter (12.8 MB)
    }
}

// ---------------- GEMM1: h1 = (X @ W1) * dinv[row] ----------------
// R3 post-mortem: __syncthreads() = vmcnt(0) drain -> the ch+1 prefetch is
// drained at every chunk barrier; the double-buffer never overlapped.
// This version ports the m201 T3+T4 pattern: triple-buffered LDS (3x8KB),
// raw s_barrier, COUNTED vmcnt (never 0 in the loop). Prologue issues
// chunks 0..2; iter ch waits vmcnt(4) (chunk ch arrived, 2 in flight),
// computes, barriers, issues ch+3 into the freed buffer -> each load has
// ~3 compute periods to cover HBM latency. Only vmem ops in the loop are
// the 2 gload16/wave/chunk (W1 is s_load via the uniform readfirstlane
// chain), so static vmcnt counts are exact. Last 2 iters peel to 2/0.
// Thread = (row = lane, col-quarter = wave); XOR slot swizzle g^(r&7)
// keeps the DMA dest linear (rule 21) and spreads ds_read_b128 banks.

__global__ __launch_bounds__(256, 6) void k_gemm1(const float* __restrict__ x,
                                                  const float* __restrict__ W1,
                                                  const float* __restrict__ dinv,
                                                  int N, float* __restrict__ h1) {
    __shared__ float xs[3][2048];  // 3 x 8 KB: 64 rows x 32 floats per buffer
    const int t = threadIdx.x;
    const int lane = t & 63;
    const int cq = __builtin_amdgcn_readfirstlane(t >> 6);  // wave = col-quarter
    const int R0 = blockIdx.x * 64;

    const float* gbase[2];
#pragma unroll
    for (int u = 0; u < 2; ++u) {
        int r = (cq * 2 + u) * 8 + (lane >> 3);   // LDS row this lane-slot fills
        int g = lane & 7;                         // 16B-slot within row
        int row = R0 + r;
        if (row >= N) row = N - 1;                // clamp: tail rows never stored
        gbase[u] = x + (size_t)row * 512 + ((g ^ (r & 7)) << 2);
    }

    float acc[4] = {0.f, 0.f, 0.f, 0.f};

    // prologue: chunks 0..2 -> bufs 0..2 (6 loads in flight per wave)
#pragma unroll
    for (int c = 0; c < 3; ++c)
#pragma unroll
        for (int u = 0; u < 2; ++u)
            gload16(gbase[u] + c * 32, &xs[c][((cq * 2 + u) * 64 + lane) * 4]);

    const int row = lane;
    const int rs = row & 7;

#define GEMM1_BODY(CH, VM)                                                       \
    do {                                                                         \
        asm volatile("s_waitcnt vmcnt(" #VM ")" ::: "memory");                   \
        __builtin_amdgcn_s_barrier();        /* all waves' chunk-CH DMA done */  \
        __builtin_amdgcn_sched_barrier(0);   /* no LDS reads hoisted above  */   \
        const float* xr = &xs[(CH) % 3][row * 32];                               \
        _Pragma("unroll") for (int j = 0; j < 8; ++j) {                          \
            int j4 = (j + cq * 2) & 7;       /* per-wave rotation */             \
            float4 xv = *(const float4*)(xr + ((j4 ^ rs) << 2));                 \
            float xe[4] = {xv.x, xv.y, xv.z, xv.w};                              \
            int k = (CH) * 32 + j4 * 4;                                          \
            _Pragma("unroll") for (int d = 0; d < 4; ++d) {                      \
                const float* wp = W1 + (k + d) * 16 + cq * 4; /* s_load */       \
                _Pragma("unroll") for (int c = 0; c < 4; ++c)                    \
                    acc[c] = fmaf(xe[d], wp[c], acc[c]);                         \
            }                                                                    \
        }                                                                        \
        __builtin_amdgcn_s_barrier();        /* all waves done reading buf */    \
        if ((CH) + 3 < 16) {                                                     \
            _Pragma("unroll") for (int u = 0; u < 2; ++u)                        \
                gload16(gbase[u] + ((CH) + 3) * 32,                              \
                        &xs[(CH) % 3][((cq * 2 + u) * 64 + lane) * 4]);          \
        }                                                                        \
    } while (0)

    for (int ch = 0; ch < 14; ++ch) GEMM1_BODY(ch, 4);
    GEMM1_BODY(14, 2);
    GEMM1_BODY(15, 0);
#undef GEMM1_BODY

    int orow = R0 + row;
    if (orow < N) {
        float di = dinv[orow];
        *(float4*)(h1 + (size_t)orow * 16 + cq * 4) =
            make_float4(acc[0] * di, acc[1] * di, acc[2] * di, acc[3] * di);
    }
}

// ---------------- Aggregation layer 1: relu1 = relu(di * sum(h1') + b1) ----------------

__global__ void k_gather1(const float* __restrict__ h1, const int* __restrict__ csr_src,
                          const int* __restrict__ rowStart, const int* __restrict__ hist,
                          const float* __restrict__ dinv, const float* __restrict__ b1,
                          int N, float* __restrict__ relu1) {
    int g = blockIdx.x * blockDim.x + threadIdx.x;
    int i = g >> 4, c = g & 15;
    if (i >= N) return;
    float ssum = h1[(size_t)i * 16 + c];  // self-loop (already * dinv[i])
    int e0 = rowStart[i], e1 = e0 + hist[i];
    for (int e = e0; e < e1; ++e) {
        int s = csr_src[e];
        ssum += h1[(size_t)s * 16 + c];
    }
    float v = fmaf(dinv[i], ssum, b1[c]);
    relu1[(size_t)i * 16 + c] = fmaxf(v, 0.0f);
}

// ---------------- h2 = (relu1 @ W2) * dinv[i]  (W2 [16,7]) ----------------

__global__ void k_h2(const float* __restrict__ relu1, const float* __restrict__ W2,
                     const float* __restrict__ dinv, int N, float* __restrict__ h2) {
    int i = blockIdx.x * blockDim.x + threadIdx.x;
    if (i >= N) return;
    float r[16];
#pragma unroll
    for (int q = 0; q < 4; ++q) {
        float4 v = *(const float4*)(relu1 + (size_t)i * 16 + q * 4);
        r[q * 4 + 0] = v.x; r[q * 4 + 1] = v.y; r[q * 4 + 2] = v.z; r[q * 4 + 3] = v.w;
    }
    float di = dinv[i];
#pragma unroll
    for (int c2 = 0; c2 < 7; ++c2) {
        float a = 0.0f;
#pragma unroll
        for (int c = 0; c < 16; ++c) a = fmaf(r[c], W2[c * 7 + c2], a);
        h2[(size_t)i * 7 + c2] = a * di;
    }
}

// ---------------- Aggregation layer 2: out = di * sum(h2') + b2 ----------------

__global__ void k_gather2(const float* __restrict__ h2, const int* __restrict__ csr_src,
                          const int* __restrict__ rowStart, const int* __restrict__ hist,
                          const float* __restrict__ dinv, const float* __restrict__ b2,
                          int N, float* __restrict__ out) {
    int g = blockIdx.x * blockDim.x + threadIdx.x;
    int i = g >> 3, c = g & 7;
    if (i >= N || c >= 7) return;
    float ssum = h2[(size_t)i * 7 + c];
    int e0 = rowStart[i], e1 = e0 + hist[i];
    for (int e = e0; e < e1; ++e) {
        int s = csr_src[e];
        ssum += h2[(size_t)s * 7 + c];
    }
    out[(size_t)i * 7 + c] = fmaf(dinv[i], ssum, b2[c]);
}

// ---------------- launch ----------------

extern "C" void kernel_launch(void* const* d_in, const int* in_sizes, int n_in,
                              void* d_out, int out_size, void* d_ws, size_t ws_size,
                              hipStream_t stream) {
    const float* x  = (const float*)d_in[0];
    const int*   ei = (const int*)d_in[1];
    const float* W1 = (const float*)d_in[2];
    const float* b1 = (const float*)d_in[3];
    const float* W2 = (const float*)d_in[4];
    const float* b2 = (const float*)d_in[5];
    float* out = (float*)d_out;

    const int N = in_sizes[0] / 512;
    const int E = in_sizes[1] / 2;
    const int* src = ei;       // edge_index[0]
    const int* dst = ei + E;   // edge_index[1]

    const int nb   = (N + 255) / 256;   // 391 node blocks
    const int nb64 = (N + 63) / 64;     // 1563 gemm row-blocks (64 rows each)

    char* ws = (char*)d_ws;
    auto alloc = [&](size_t bytes) {
        char* p = ws;
        ws += (bytes + 511) & ~(size_t)511;
        return p;
    };
    // persistent region
    int*   hist     = (int*)alloc((size_t)N * 4);
    float* dinv     = (float*)alloc((size_t)N * 4);
    int*   rowStart = (int*)alloc((size_t)N * 4);
    int*   cnt      = (int*)alloc((size_t)N * 4);
    int*   bsums    = (int*)alloc((size_t)(nb + 1) * 4);
    int*   csr_src  = (int*)alloc((size_t)E * 4);
    // feature region
    float* h1    = (float*)alloc((size_t)N * 16 * 4);
    float* relu1 = (float*)alloc((size_t)N * 16 * 4);
    float* h2    = (float*)alloc((size_t)N * 7 * 4);

    hipMemsetAsync(hist, 0, (size_t)N * 4, stream);
    k_deg<<<2048, 256, 0, stream>>>(dst, E, hist);
    k_scan_local<<<nb, 256, 0, stream>>>(hist, N, rowStart, bsums);
    k_scan_bsums<<<1, 512, 0, stream>>>(bsums, nb);
    k_finalize<<<nb, 256, 0, stream>>>(rowStart, bsums, hist, N, dinv, cnt);
    k_csr_scatter<<<2048, 256, 0, stream>>>(src, dst, E, rowStart, cnt, csr_src);
    k_gemm1<<<nb64, 256, 0, stream>>>(x, W1, dinv, N, h1);
    k_gather1<<<(N * 16 + 255) / 256, 256, 0, stream>>>(h1, csr_src, rowStart, hist, dinv, b1, N, relu1);
    k_h2<<<nb, 256, 0, stream>>>(relu1, W2, dinv, N, h2);
    k_gather2<<<(N * 8 + 255) / 256, 256, 0, stream>>>(h2, csr_src, rowStart, hist, dinv, b2, N, out);
}

// Round 6
// 583.530 us; speedup vs baseline: 1.3011x; 1.3011x over previous
//
#include <hip/hip_runtime.h>

#define CHUNK 8192           // edges per block in coarse pass
#define BMAX 512             // max coarse buckets (N/256 <= 512)

typedef __attribute__((address_space(3))) unsigned int lds_u32;
typedef const __attribute__((address_space(1))) unsigned int glb_u32;

// async 16B global -> LDS (global_load_lds_dwordx4). HW dest = wave-uniform
// base + lane*16, which our flat slot layout satisfies exactly.
__device__ __forceinline__ void gload16(const float* g, float* l) {
    __builtin_amdgcn_global_load_lds((glb_u32*)g, (lds_u32*)l, 16, 0, 0);
}

// ---------------- coarse bucket histogram ----------------
// R4 post-mortem: the two-level bucket sort is load-bearing. A direct
// global-atomic CSR scatter has 16x write amplification (198 MB for a
// 12.8 MB output: random 4B stores dirty whole 64B lines across 8
// non-coherent XCDs). Bucketing keeps every scatter L2/XCD-local.

__global__ __launch_bounds__(256) void k_coarse_hist(const int* __restrict__ dst, int E,
                                                     int* __restrict__ bc,
                                                     int* __restrict__ blockBase, int B) {
    __shared__ int cnt[BMAX];
    int t = threadIdx.x;
    cnt[t] = 0; cnt[t + 256] = 0;
    __syncthreads();
    int e0 = blockIdx.x * CHUNK;
#pragma unroll
    for (int it = 0; it < CHUNK / 256; ++it) {
        int e = e0 + it * 256 + t;
        if (e < E) atomicAdd(&cnt[dst[e] >> 8], 1);
    }
    __syncthreads();
    for (int b = t; b < B; b += 256) {
        int c = cnt[b];
        if (c > 0) blockBase[(size_t)blockIdx.x * B + b] = atomicAdd(&bc[b], c);
    }
}

// single block, 512 threads; exclusive scan in place (n <= 512)
__global__ void k_scan_bsums(int* bsums, int nb) {
    __shared__ int s[2][512];
    int t = threadIdx.x;
    int v = (t < nb) ? bsums[t] : 0;
    int p = 0;
    s[0][t] = v;
    __syncthreads();
    for (int off = 1; off < 512; off <<= 1) {
        s[p ^ 1][t] = s[p][t] + ((t >= off) ? s[p][t - off] : 0);
        p ^= 1;
        __syncthreads();
    }
    if (t < nb) bsums[t] = s[p][t] - v;  // exclusive
}

// ---------------- coarse scatter ----------------

__global__ __launch_bounds__(256) void k_coarse_scatter(const int* __restrict__ src,
                                                        const int* __restrict__ dst, int E,
                                                        const int* __restrict__ bucketBase,
                                                        const int* __restrict__ blockBase, int B,
                                                        unsigned int* __restrict__ ebuf) {
    __shared__ int run[BMAX];
    int t = threadIdx.x;
    run[t] = 0; run[t + 256] = 0;
    __syncthreads();
    int e0 = blockIdx.x * CHUNK;
#pragma unroll
    for (int it = 0; it < CHUNK / 256; ++it) {
        int e = e0 + it * 256 + t;
        if (e < E) {
            int d = dst[e];
            int b = d >> 8;
            int rank = atomicAdd(&run[b], 1);
            int pos = bucketBase[b] + blockBase[(size_t)blockIdx.x * B + b] + rank;
            ebuf[pos] = ((unsigned int)(d & 255) << 24) | (unsigned int)src[e];
        }
    }
}

// ---------------- per-node degree histogram + dinv from bucketed edges ----------------

__global__ __launch_bounds__(256) void k_bucket_hist(const unsigned int* __restrict__ ebuf,
                                                     const int* __restrict__ bucketBase,
                                                     int E, int N, int B,
                                                     int* __restrict__ hist,
                                                     float* __restrict__ dinv) {
    __shared__ int cnt[256];
    int t = threadIdx.x;
    int b = blockIdx.x;
    cnt[t] = 0;
    __syncthreads();
    int e0 = bucketBase[b];
    int e1 = (b + 1 < B) ? bucketBase[b + 1] : E;
    for (int e = e0 + t; e < e1; e += 256) atomicAdd(&cnt[ebuf[e] >> 24], 1);
    __syncthreads();
    int node = b * 256 + t;
    if (node < N) {
        hist[node] = cnt[t];
        dinv[node] = rsqrtf((float)(cnt[t] + 1));  // +1 self-loop
    }
}

// ---------------- fine scatter (fused rowStart scan): bucket -> CSR ----------------

__global__ __launch_bounds__(256) void k_fine_scatter(const unsigned int* __restrict__ ebuf,
                                                      const int* __restrict__ bucketBase,
                                                      const int* __restrict__ hist,
                                                      int E, int N, int B,
                                                      int* __restrict__ rowStart,
                                                      int* __restrict__ csr_src) {
    __shared__ int s[2][256];
    __shared__ int cnt[256];
    int t = threadIdx.x;
    int b = blockIdx.x;
    int node = b * 256 + t;
    int v = (node < N) ? hist[node] : 0;
    int p = 0;
    s[0][t] = v;
    __syncthreads();
    for (int off = 1; off < 256; off <<= 1) {
        s[p ^ 1][t] = s[p][t] + ((t >= off) ? s[p][t - off] : 0);
        p ^= 1;
        __syncthreads();
    }
    int rs = bucketBase[b] + s[p][t] - v;
    if (node < N) rowStart[node] = rs;
    cnt[t] = rs;
    __syncthreads();
    int e0 = bucketBase[b];
    int e1 = (b + 1 < B) ? bucketBase[b + 1] : E;
    for (int e = e0 + t; e < e1; e += 256) {
        unsigned int w = ebuf[e];
        int pos = atomicAdd(&cnt[w >> 24], 1);
        csr_src[pos] = (int)(w & 0xFFFFFFu);
    }
}

// ---------------- GEMM1: h1 = (X @ W1) * dinv[row] ----------------
// m201 T3+T4 pattern: triple-buffered LDS (3x8KB), raw s_barrier, COUNTED
// vmcnt (never 0 in the loop). Prologue issues chunks 0..2; iter ch waits
// vmcnt(4) (chunk ch arrived, 2 in flight), computes, barriers, issues
// ch+3 into the freed buffer -> each load has ~3 compute periods to cover
// HBM latency. Only vmem ops in the loop are the 2 gload16/wave/chunk
// (W1 is s_load via the uniform readfirstlane chain), so static vmcnt
// counts are exact. Last 2 iters peel to 2/0. Verified correct in R4.
// Thread = (row = lane, col-quarter = wave); XOR slot swizzle g^(r&7)
// keeps the DMA dest linear (rule 21) and spreads ds_read_b128 banks.

__global__ __launch_bounds__(256, 6) void k_gemm1(const float* __restrict__ x,
                                                  const float* __restrict__ W1,
                                                  const float* __restrict__ dinv,
                                                  int N, float* __restrict__ h1) {
    __shared__ float xs[3][2048];  // 3 x 8 KB: 64 rows x 32 floats per buffer
    const int t = threadIdx.x;
    const int lane = t & 63;
    const int cq = __builtin_amdgcn_readfirstlane(t >> 6);  // wave = col-quarter
    const int R0 = blockIdx.x * 64;

    const float* gbase[2];
#pragma unroll
    for (int u = 0; u < 2; ++u) {
        int r = (cq * 2 + u) * 8 + (lane >> 3);   // LDS row this lane-slot fills
        int g = lane & 7;                         // 16B-slot within row
        int row = R0 + r;
        if (row >= N) row = N - 1;                // clamp: tail rows never stored
        gbase[u] = x + (size_t)row * 512 + ((g ^ (r & 7)) << 2);
    }

    float acc[4] = {0.f, 0.f, 0.f, 0.f};

    // prologue: chunks 0..2 -> bufs 0..2 (6 loads in flight per wave)
#pragma unroll
    for (int c = 0; c < 3; ++c)
#pragma unroll
        for (int u = 0; u < 2; ++u)
            gload16(gbase[u] + c * 32, &xs[c][((cq * 2 + u) * 64 + lane) * 4]);

    const int row = lane;
    const int rs = row & 7;

#define GEMM1_BODY(CH, VM)                                                       \
    do {                                                                         \
        asm volatile("s_waitcnt vmcnt(" #VM ")" ::: "memory");                   \
        __builtin_amdgcn_s_barrier();        /* all waves' chunk-CH DMA done */  \
        __builtin_amdgcn_sched_barrier(0);   /* no LDS reads hoisted above  */   \
        const float* xr = &xs[(CH) % 3][row * 32];                               \
        _Pragma("unroll") for (int j = 0; j < 8; ++j) {                          \
            int j4 = (j + cq * 2) & 7;       /* per-wave rotation */             \
            float4 xv = *(const float4*)(xr + ((j4 ^ rs) << 2));                 \
            float xe[4] = {xv.x, xv.y, xv.z, xv.w};                              \
            int k = (CH) * 32 + j4 * 4;                                          \
            _Pragma("unroll") for (int d = 0; d < 4; ++d) {                      \
                const float* wp = W1 + (k + d) * 16 + cq * 4; /* s_load */       \
                _Pragma("unroll") for (int c = 0; c < 4; ++c)                    \
                    acc[c] = fmaf(xe[d], wp[c], acc[c]);                         \
            }                                                                    \
        }                                                                        \
        __builtin_amdgcn_s_barrier();        /* all waves done reading buf */    \
        if ((CH) + 3 < 16) {                                                     \
            _Pragma("unroll") for (int u = 0; u < 2; ++u)                        \
                gload16(gbase[u] + ((CH) + 3) * 32,                              \
                        &xs[(CH) % 3][((cq * 2 + u) * 64 + lane) * 4]);          \
        }                                                                        \
    } while (0)

    for (int ch = 0; ch < 14; ++ch) GEMM1_BODY(ch, 4);
    GEMM1_BODY(14, 2);
    GEMM1_BODY(15, 0);
#undef GEMM1_BODY

    int orow = R0 + row;
    if (orow < N) {
        float di = dinv[orow];
        *(float4*)(h1 + (size_t)orow * 16 + cq * 4) =
            make_float4(acc[0] * di, acc[1] * di, acc[2] * di, acc[3] * di);
    }
}

// ---------------- Aggregation layer 1: relu1 = relu(di * sum(h1') + b1) ----------------

__global__ void k_gather1(const float* __restrict__ h1, const int* __restrict__ csr_src,
                          const int* __restrict__ rowStart, const int* __restrict__ hist,
                          const float* __restrict__ dinv, const float* __restrict__ b1,
                          int N, float* __restrict__ relu1) {
    int g = blockIdx.x * blockDim.x + threadIdx.x;
    int i = g >> 4, c = g & 15;
    if (i >= N) return;
    float ssum = h1[(size_t)i * 16 + c];  // self-loop (already * dinv[i])
    int e0 = rowStart[i], e1 = e0 + hist[i];
    for (int e = e0; e < e1; ++e) {
        int s = csr_src[e];
        ssum += h1[(size_t)s * 16 + c];
    }
    float v = fmaf(dinv[i], ssum, b1[c]);
    relu1[(size_t)i * 16 + c] = fmaxf(v, 0.0f);
}

// ---------------- h2 = (relu1 @ W2) * dinv[i]  (W2 [16,7]) ----------------

__global__ void k_h2(const float* __restrict__ relu1, const float* __restrict__ W2,
                     const float* __restrict__ dinv, int N, float* __restrict__ h2) {
    int i = blockIdx.x * blockDim.x + threadIdx.x;
    if (i >= N) return;
    float r[16];
#pragma unroll
    for (int q = 0; q < 4; ++q) {
        float4 v = *(const float4*)(relu1 + (size_t)i * 16 + q * 4);
        r[q * 4 + 0] = v.x; r[q * 4 + 1] = v.y; r[q * 4 + 2] = v.z; r[q * 4 + 3] = v.w;
    }
    float di = dinv[i];
#pragma unroll
    for (int c2 = 0; c2 < 7; ++c2) {
        float a = 0.0f;
#pragma unroll
        for (int c = 0; c < 16; ++c) a = fmaf(r[c], W2[c * 7 + c2], a);
        h2[(size_t)i * 7 + c2] = a * di;
    }
}

// ---------------- Aggregation layer 2: out = di * sum(h2') + b2 ----------------

__global__ void k_gather2(const float* __restrict__ h2, const int* __restrict__ csr_src,
                          const int* __restrict__ rowStart, const int* __restrict__ hist,
                          const float* __restrict__ dinv, const float* __restrict__ b2,
                          int N, float* __restrict__ out) {
    int g = blockIdx.x * blockDim.x + threadIdx.x;
    int i = g >> 3, c = g & 7;
    if (i >= N || c >= 7) return;
    float ssum = h2[(size_t)i * 7 + c];
    int e0 = rowStart[i], e1 = e0 + hist[i];
    for (int e = e0; e < e1; ++e) {
        int s = csr_src[e];
        ssum += h2[(size_t)s * 7 + c];
    }
    out[(size_t)i * 7 + c] = fmaf(dinv[i], ssum, b2[c]);
}

// ---------------- launch ----------------

extern "C" void kernel_launch(void* const* d_in, const int* in_sizes, int n_in,
                              void* d_out, int out_size, void* d_ws, size_t ws_size,
                              hipStream_t stream) {
    const float* x  = (const float*)d_in[0];
    const int*   ei = (const int*)d_in[1];
    const float* W1 = (const float*)d_in[2];
    const float* b1 = (const float*)d_in[3];
    const float* W2 = (const float*)d_in[4];
    const float* b2 = (const float*)d_in[5];
    float* out = (float*)d_out;

    const int N = in_sizes[0] / 512;
    const int E = in_sizes[1] / 2;
    const int* src = ei;       // edge_index[0]
    const int* dst = ei + E;   // edge_index[1]

    const int nb   = (N + 255) / 256;          // 391 node blocks == coarse buckets
    const int B    = nb;
    const int nbA  = (E + CHUNK - 1) / CHUNK;  // 391 coarse blocks
    const int nb64 = (N + 63) / 64;            // 1563 gemm row-blocks (64 rows each)

    char* ws = (char*)d_ws;
    auto alloc = [&](size_t bytes) {
        char* p = ws;
        ws += (bytes + 511) & ~(size_t)511;
        return p;
    };
    // persistent region
    int*   hist      = (int*)alloc((size_t)N * 4);
    float* dinv      = (float*)alloc((size_t)N * 4);
    int*   rowStart  = (int*)alloc((size_t)N * 4);
    int*   bc        = (int*)alloc((size_t)(B + 1) * 4);
    int*   blockBase = (int*)alloc((size_t)nbA * B * 4);
    int*   csr_src   = (int*)alloc((size_t)E * 4);
    // overlapped region: ebuf (dead after fine_scatter) unions with h1/relu1/h2
    size_t featBytes = (size_t)N * 16 * 4 * 2 + (size_t)N * 7 * 4;
    size_t ebufBytes = (size_t)E * 4;
    char* regB = alloc(featBytes > ebufBytes ? featBytes : ebufBytes);
    unsigned int* ebuf = (unsigned int*)regB;
    float* h1    = (float*)regB;
    float* relu1 = h1 + (size_t)N * 16;
    float* h2    = relu1 + (size_t)N * 16;

    hipMemsetAsync(bc, 0, (size_t)B * 4, stream);
    k_coarse_hist<<<nbA, 256, 0, stream>>>(dst, E, bc, blockBase, B);
    k_scan_bsums<<<1, 512, 0, stream>>>(bc, B);                       // bc -> bucketBase
    k_coarse_scatter<<<nbA, 256, 0, stream>>>(src, dst, E, bc, blockBase, B, ebuf);
    k_bucket_hist<<<B, 256, 0, stream>>>(ebuf, bc, E, N, B, hist, dinv);
    k_fine_scatter<<<B, 256, 0, stream>>>(ebuf, bc, hist, E, N, B, rowStart, csr_src);
    k_gemm1<<<nb64, 256, 0, stream>>>(x, W1, dinv, N, h1);
    k_gather1<<<(N * 16 + 255) / 256, 256, 0, stream>>>(h1, csr_src, rowStart, hist, dinv, b1, N, relu1);
    k_h2<<<nb, 256, 0, stream>>>(relu1, W2, dinv, N, h2);
    k_gather2<<<(N * 8 + 255) / 256, 256, 0, stream>>>(h2, csr_src, rowStart, hist, dinv, b2, N, out);
}

// Round 8
// 499.042 us; speedup vs baseline: 1.5214x; 1.1693x over previous
//
#include <hip/hip_runtime.h>

#define CHUNK 8192           // edges per block in coarse pass
#define BMAX 512             // max coarse buckets (N/256 <= 512)

typedef __attribute__((address_space(3))) unsigned int lds_u32;
typedef const __attribute__((address_space(1))) unsigned int glb_u32;

// async 16B global -> LDS (global_load_lds_dwordx4). HW dest = wave-uniform
// base + lane*16, which our flat slot layout satisfies exactly.
__device__ __forceinline__ void gload16(const float* g, float* l) {
    __builtin_amdgcn_global_load_lds((glb_u32*)g, (lds_u32*)l, 16, 0, 0);
}

// ---------------- coarse bucket histogram ----------------
// R4 post-mortem: the two-level bucket sort is load-bearing. A direct
// global-atomic CSR scatter has 16x write amplification (198 MB for a
// 12.8 MB output: random 4B stores dirty whole 64B lines across 8
// non-coherent XCDs). Bucketing keeps every scatter L2/XCD-local.

__global__ __launch_bounds__(256) void k_coarse_hist(const int* __restrict__ dst, int E,
                                                     int* __restrict__ bc,
                                                     int* __restrict__ blockBase, int B) {
    __shared__ int cnt[BMAX];
    int t = threadIdx.x;
    cnt[t] = 0; cnt[t + 256] = 0;
    __syncthreads();
    int e0 = blockIdx.x * CHUNK;
#pragma unroll
    for (int it = 0; it < CHUNK / 256; ++it) {
        int e = e0 + it * 256 + t;
        if (e < E) atomicAdd(&cnt[dst[e] >> 8], 1);
    }
    __syncthreads();
    for (int b = t; b < B; b += 256) {
        int c = cnt[b];
        if (c > 0) blockBase[(size_t)blockIdx.x * B + b] = atomicAdd(&bc[b], c);
    }
}

// single block, 512 threads; exclusive scan in place (n <= 512)
__global__ void k_scan_bsums(int* bsums, int nb) {
    __shared__ int s[2][512];
    int t = threadIdx.x;
    int v = (t < nb) ? bsums[t] : 0;
    int p = 0;
    s[0][t] = v;
    __syncthreads();
    for (int off = 1; off < 512; off <<= 1) {
        s[p ^ 1][t] = s[p][t] + ((t >= off) ? s[p][t - off] : 0);
        p ^= 1;
        __syncthreads();
    }
    if (t < nb) bsums[t] = s[p][t] - v;  // exclusive
}

// ---------------- coarse scatter ----------------

__global__ __launch_bounds__(256) void k_coarse_scatter(const int* __restrict__ src,
                                                        const int* __restrict__ dst, int E,
                                                        const int* __restrict__ bucketBase,
                                                        const int* __restrict__ blockBase, int B,
                                                        unsigned int* __restrict__ ebuf) {
    __shared__ int run[BMAX];
    int t = threadIdx.x;
    run[t] = 0; run[t + 256] = 0;
    __syncthreads();
    int e0 = blockIdx.x * CHUNK;
#pragma unroll
    for (int it = 0; it < CHUNK / 256; ++it) {
        int e = e0 + it * 256 + t;
        if (e < E) {
            int d = dst[e];
            int b = d >> 8;
            int rank = atomicAdd(&run[b], 1);
            int pos = bucketBase[b] + blockBase[(size_t)blockIdx.x * B + b] + rank;
            ebuf[pos] = ((unsigned int)(d & 255) << 24) | (unsigned int)src[e];
        }
    }
}

// ---------------- per-node degree histogram + dinv from bucketed edges ----------------

__global__ __launch_bounds__(256) void k_bucket_hist(const unsigned int* __restrict__ ebuf,
                                                     const int* __restrict__ bucketBase,
                                                     int E, int N, int B,
                                                     int* __restrict__ hist,
                                                     float* __restrict__ dinv) {
    __shared__ int cnt[256];
    int t = threadIdx.x;
    int b = blockIdx.x;
    cnt[t] = 0;
    __syncthreads();
    int e0 = bucketBase[b];
    int e1 = (b + 1 < B) ? bucketBase[b + 1] : E;
    for (int e = e0 + t; e < e1; e += 256) atomicAdd(&cnt[ebuf[e] >> 24], 1);
    __syncthreads();
    int node = b * 256 + t;
    if (node < N) {
        hist[node] = cnt[t];
        dinv[node] = rsqrtf((float)(cnt[t] + 1));  // +1 self-loop
    }
}

// ---------------- fine scatter (fused rowStart scan): bucket -> CSR ----------------

__global__ __launch_bounds__(256) void k_fine_scatter(const unsigned int* __restrict__ ebuf,
                                                      const int* __restrict__ bucketBase,
                                                      const int* __restrict__ hist,
                                                      int E, int N, int B,
                                                      int* __restrict__ rowStart,
                                                      int* __restrict__ csr_src) {
    __shared__ int s[2][256];
    __shared__ int cnt[256];
    int t = threadIdx.x;
    int b = blockIdx.x;
    int node = b * 256 + t;
    int v = (node < N) ? hist[node] : 0;
    int p = 0;
    s[0][t] = v;
    __syncthreads();
    for (int off = 1; off < 256; off <<= 1) {
        s[p ^ 1][t] = s[p][t] + ((t >= off) ? s[p][t - off] : 0);
        p ^= 1;
        __syncthreads();
    }
    int rs = bucketBase[b] + s[p][t] - v;
    if (node < N) rowStart[node] = rs;
    cnt[t] = rs;
    __syncthreads();
    int e0 = bucketBase[b];
    int e1 = (b + 1 < B) ? bucketBase[b + 1] : E;
    for (int e = e0 + t; e < e1; e += 256) {
        unsigned int w = ebuf[e];
        int pos = atomicAdd(&cnt[w >> 24], 1);
        csr_src[pos] = (int)(w & 0xFFFFFFu);
    }
}

// ---------------- GEMM1: h1 = (X @ W1) * dinv[row] ----------------
// R3-proven version (best measured total). 64 rows/block (grid 1563),
// 2x8KB double-buffered LDS, ~6 resident blocks/CU; issue(ch+1)/compute(ch)
// pipeline with plain __syncthreads. R6 A/B showed the counted-vmcnt
// triple-buffer variant is ~25us WORSE: at 6 blocks/CU the implicit
// cross-block wave overlap already covers HBM latency, and extra raw
// barriers + sched_barrier(0) only add overhead (m141 failure mode).
// Thread = (row = lane, col-quarter = wave): full K per thread, 4 output
// cols -> no reduction, no atomics. W1 index wave-uniform (s_load).
// XOR slot swizzle g^(r&7) keeps the DMA dest linear (rule 21) and
// spreads the stride-128B ds_read_b128 across banks.

__global__ __launch_bounds__(256, 6) void k_gemm1(const float* __restrict__ x,
                                                  const float* __restrict__ W1,
                                                  const float* __restrict__ dinv,
                                                  int N, float* __restrict__ h1) {
    __shared__ float xs[2][2048];  // 2 x 8 KB: 64 rows x 32 floats (one k-chunk)
    const int t = threadIdx.x;
    const int lane = t & 63;
    const int cq = __builtin_amdgcn_readfirstlane(t >> 6);  // wave 0..3 = col-quarter
    const int R0 = blockIdx.x * 64;

    // two DMA issues per wave per chunk; per-lane pre-swizzled source bases
    const float* gbase[2];
#pragma unroll
    for (int u = 0; u < 2; ++u) {
        int r = (cq * 2 + u) * 8 + (lane >> 3);   // LDS row this lane-slot fills
        int g = lane & 7;                         // 16B-slot within row
        int row = R0 + r;
        if (row >= N) row = N - 1;                // clamp: tail rows never stored
        gbase[u] = x + (size_t)row * 512 + ((g ^ (r & 7)) << 2);
    }

    float acc[4] = {0.f, 0.f, 0.f, 0.f};

    // prologue: chunk 0 -> buf 0
#pragma unroll
    for (int u = 0; u < 2; ++u)
        gload16(gbase[u], &xs[0][((cq * 2 + u) * 64 + lane) * 4]);
    __syncthreads();  // vmcnt(0) drain + barrier

    const int row = lane;
    const int rs = row & 7;
    int p = 0;
    for (int ch = 0; ch < 16; ++ch) {
        if (ch + 1 < 16) {
#pragma unroll
            for (int u = 0; u < 2; ++u)
                gload16(gbase[u] + (ch + 1) * 32, &xs[p ^ 1][((cq * 2 + u) * 64 + lane) * 4]);
        }
        const float* xr = &xs[p][row * 32];
#pragma unroll
        for (int j = 0; j < 8; ++j) {
            int j4 = (j + cq * 2) & 7;            // per-wave rotation (bank spread)
            float4 xv = *(const float4*)(xr + ((j4 ^ rs) << 2));
            float xe[4] = {xv.x, xv.y, xv.z, xv.w};
            int k = ch * 32 + j4 * 4;
#pragma unroll
            for (int d = 0; d < 4; ++d) {
                const float* wp = W1 + (k + d) * 16 + cq * 4;  // wave-uniform -> s_load
#pragma unroll
                for (int c = 0; c < 4; ++c) acc[c] = fmaf(xe[d], wp[c], acc[c]);
            }
        }
        __syncthreads();  // prefetch of ch+1 stays in flight across this
        p ^= 1;
    }

    int orow = R0 + row;
    if (orow < N) {
        float di = dinv[orow];
        *(float4*)(h1 + (size_t)orow * 16 + cq * 4) =
            make_float4(acc[0] * di, acc[1] * di, acc[2] * di, acc[3] * di);
    }
}

// ---------------- Aggregation layer 1 FUSED with h2 projection ----------------
// relu1 row lives entirely in the 16 lanes of a node's channel group, and
// relu1 was consumed ONLY by k_h2 -> fuse the 16->7 W2 projection here via
// quarter-wave __shfl_xor reduction. Saves the whole k_h2 pass (6.4 MB rd
// + 6.4 MB wr + 2.8 MB wr -> 3.2 MB wr) and one launch. h2 stored padded
// to 8 floats/row (lane 7 = 0) so gather2 reads aligned 32B rows.
// Gather loop manually 4-deep unrolled: guarantees 4 independent L2/L3
// gathers in flight per thread (latency-bound regime).

__global__ void k_gather1h2(const float* __restrict__ h1, const int* __restrict__ csr_src,
                            const int* __restrict__ rowStart, const int* __restrict__ hist,
                            const float* __restrict__ dinv, const float* __restrict__ b1,
                            const float* __restrict__ W2, int N,
                            float* __restrict__ h2p) {
    int g = blockIdx.x * blockDim.x + threadIdx.x;
    int i = g >> 4, c = g & 15;   // all 16 lanes of a group share i (no divergence)
    if (i >= N) return;
    float ssum = h1[(size_t)i * 16 + c];  // self-loop (already * dinv[i])
    int e = rowStart[i], e1 = e + hist[i];
    for (; e + 4 <= e1; e += 4) {
        int s0 = csr_src[e], s1 = csr_src[e + 1], s2 = csr_src[e + 2], s3 = csr_src[e + 3];
        float a0 = h1[(size_t)s0 * 16 + c];
        float a1 = h1[(size_t)s1 * 16 + c];
        float a2 = h1[(size_t)s2 * 16 + c];
        float a3 = h1[(size_t)s3 * 16 + c];
        ssum += (a0 + a1) + (a2 + a3);
    }
    for (; e < e1; ++e) ssum += h1[(size_t)csr_src[e] * 16 + c];

    float di = dinv[i];
    float v = fmaxf(fmaf(di, ssum, b1[c]), 0.0f);  // relu1[i][c], in-register

    // 16->7 projection: lane c holds v; p[c2] = sum_c v * W2[c][c2]
    float p0 = v * W2[c * 7 + 0], p1 = v * W2[c * 7 + 1], p2 = v * W2[c * 7 + 2],
          p3 = v * W2[c * 7 + 3], p4 = v * W2[c * 7 + 4], p5 = v * W2[c * 7 + 5],
          p6 = v * W2[c * 7 + 6];
#pragma unroll
    for (int m = 1; m < 16; m <<= 1) {
        p0 += __shfl_xor(p0, m); p1 += __shfl_xor(p1, m); p2 += __shfl_xor(p2, m);
        p3 += __shfl_xor(p3, m); p4 += __shfl_xor(p4, m); p5 += __shfl_xor(p5, m);
        p6 += __shfl_xor(p6, m);
    }
    if (c < 8) {  // lanes 0..6 write h2; lane 7 writes the 0 pad
        float o = (c == 0) ? p0 : (c == 1) ? p1 : (c == 2) ? p2 : (c == 3) ? p3
                : (c == 4) ? p4 : (c == 5) ? p5 : (c == 6) ? p6 : 0.0f;
        h2p[(size_t)i * 8 + c] = o * di;  // pre-scale by dinv[i] (transform-first)
    }
}

// ---------------- Aggregation layer 2: out = di * sum(h2') + b2 ----------------

__global__ void k_gather2(const float* __restrict__ h2p, const int* __restrict__ csr_src,
                          const int* __restrict__ rowStart, const int* __restrict__ hist,
                          const float* __restrict__ dinv, const float* __restrict__ b2,
                          int N, float* __restrict__ out) {
    int g = blockIdx.x * blockDim.x + threadIdx.x;
    int i = g >> 3, c = g & 7;    // 8-lane groups share i; pad lane sums zeros
    if (i >= N) return;
    float ssum = h2p[(size_t)i * 8 + c];
    int e = rowStart[i], e1 = e + hist[i];
    for (; e + 4 <= e1; e += 4) {
        int s0 = csr_src[e], s1 = csr_src[e + 1], s2 = csr_src[e + 2], s3 = csr_src[e + 3];
        float a0 = h2p[(size_t)s0 * 8 + c];
        float a1 = h2p[(size_t)s1 * 8 + c];
        float a2 = h2p[(size_t)s2 * 8 + c];
        float a3 = h2p[(size_t)s3 * 8 + c];
        ssum += (a0 + a1) + (a2 + a3);
    }
    for (; e < e1; ++e) ssum += h2p[(size_t)csr_src[e] * 8 + c];
    if (c < 7) out[(size_t)i * 7 + c] = fmaf(dinv[i], ssum, b2[c]);
}

// ---------------- launch ----------------

extern "C" void kernel_launch(void* const* d_in, const int* in_sizes, int n_in,
                              void* d_out, int out_size, void* d_ws, size_t ws_size,
                              hipStream_t stream) {
    const float* x  = (const float*)d_in[0];
    const int*   ei = (const int*)d_in[1];
    const float* W1 = (const float*)d_in[2];
    const float* b1 = (const float*)d_in[3];
    const float* W2 = (const float*)d_in[4];
    const float* b2 = (const float*)d_in[5];
    float* out = (float*)d_out;

    const int N = in_sizes[0] / 512;
    const int E = in_sizes[1] / 2;
    const int* src = ei;       // edge_index[0]
    const int* dst = ei + E;   // edge_index[1]

    const int nb   = (N + 255) / 256;          // 391 node blocks == coarse buckets
    const int B    = nb;
    const int nbA  = (E + CHUNK - 1) / CHUNK;  // 391 coarse blocks
    const int nb64 = (N + 63) / 64;            // 1563 gemm row-blocks (64 rows each)

    char* ws = (char*)d_ws;
    auto alloc = [&](size_t bytes) {
        char* p = ws;
        ws += (bytes + 511) & ~(size_t)511;
        return p;
    };
    // persistent region
    int*   hist      = (int*)alloc((size_t)N * 4);
    float* dinv      = (float*)alloc((size_t)N * 4);
    int*   rowStart  = (int*)alloc((size_t)N * 4);
    int*   bc        = (int*)alloc((size_t)(B + 1) * 4);
    int*   blockBase = (int*)alloc((size_t)nbA * B * 4);
    int*   csr_src   = (int*)alloc((size_t)E * 4);
    // overlapped region: ebuf (dead after fine_scatter) unions with h1/h2p
    size_t featBytes = (size_t)N * 16 * 4 + (size_t)N * 8 * 4;
    size_t ebufBytes = (size_t)E * 4;
    char* regB = alloc(featBytes > ebufBytes ? featBytes : ebufBytes);
    unsigned int* ebuf = (unsigned int*)regB;
    float* h1  = (float*)regB;
    float* h2p = h1 + (size_t)N * 16;

    hipMemsetAsync(bc, 0, (size_t)B * 4, stream);
    k_coarse_hist<<<nbA, 256, 0, stream>>>(dst, E, bc, blockBase, B);
    k_scan_bsums<<<1, 512, 0, stream>>>(bc, B);                       // bc -> bucketBase
    k_coarse_scatter<<<nbA, 256, 0, stream>>>(src, dst, E, bc, blockBase, B, ebuf);
    k_bucket_hist<<<B, 256, 0, stream>>>(ebuf, bc, E, N, B, hist, dinv);
    k_fine_scatter<<<B, 256, 0, stream>>>(ebuf, bc, hist, E, N, B, rowStart, csr_src);
    k_gemm1<<<nb64, 256, 0, stream>>>(x, W1, dinv, N, h1);
    k_gather1h2<<<(N * 16 + 255) / 256, 256, 0, stream>>>(h1, csr_src, rowStart, hist,
                                                          dinv, b1, W2, N, h2p);
    k_gather2<<<(N * 8 + 255) / 256, 256, 0, stream>>>(h2p, csr_src, rowStart, hist,
                                                       dinv, b2, N, out);
}